// Round 2
// baseline (1360.061 us; speedup 1.0000x reference)
//
#include <hip/hip_runtime.h>
#include <stdint.h>

#define SDR_SIZE   2048
#define CAPACITY   131072
#define TOPK       32
#define CDIM       384

// ws layout (int32 words):
// [0]       n_act
// [4..131]  sorted active column indices (cap 128)
// [192]     candidate count
// [256..]   candidate keys: (overlap << 17) | (131071 - row)

__global__ void k_prep(const float* __restrict__ q, int* __restrict__ w) {
    __shared__ int s_cnt;
    __shared__ int s_act[256];
    if (threadIdx.x == 0) s_cnt = 0;
    __syncthreads();
    for (int j = threadIdx.x; j < SDR_SIZE; j += 256) {
        if (q[j] != 0.0f) {
            int p = atomicAdd(&s_cnt, 1);
            if (p < 256) s_act[p] = j;
        }
    }
    __syncthreads();
    if (threadIdx.x == 0) {
        int n = s_cnt < 128 ? s_cnt : 128;
        // insertion sort (n ~ 40) — sorted cols improve load coalescing
        for (int i = 1; i < n; i++) {
            int v = s_act[i]; int k = i - 1;
            while (k >= 0 && s_act[k] > v) { s_act[k + 1] = s_act[k]; k--; }
            s_act[k + 1] = v;
        }
        w[0] = n;
        w[192] = 0;  // reset candidate counter
        for (int i = 0; i < n; i++) w[4 + i] = s_act[i];
    }
}

__global__ __launch_bounds__(256) void k_overlap(const float* __restrict__ bank,
                                                 const int* __restrict__ mask,  // bool uploaded as int32
                                                 int* __restrict__ w, int cap) {
    int wave = (int)((blockIdx.x * blockDim.x + threadIdx.x) >> 6);
    int lane = threadIdx.x & 63;
    if (wave >= CAPACITY) return;
    int n_act = w[0];
    const float* rp = bank + (size_t)wave * SDR_SIZE;
    int ov = 0;
    for (int base = 0; base < n_act; base += 64) {
        int l = base + lane;
        float v = 0.0f;
        if (l < n_act) {
            int c = w[4 + l];     // L1-resident broadcast table
            v = rp[c];            // the only HBM gather
        }
        unsigned long long b = __ballot(l < n_act && v != 0.0f);
        ov += __popcll(b);
    }
    if (lane == 0) {
        float sim = (float)ov / 40.0f;
        if (mask[wave] != 0 && sim >= 0.3f) {
            int p = atomicAdd(&w[192], 1);
            if (p < cap) w[256 + p] = (ov << 17) | (131071 - wave);
        }
    }
}

__global__ void k_select(const float* __restrict__ content,
                         const int* __restrict__ w,
                         float* __restrict__ out, int cap) {
    __shared__ unsigned int s_top[TOPK];
    __shared__ unsigned int s_red[256];
    int t = threadIdx.x;
    int m = w[192];
    if (m > cap) m = cap;
    int kcount = (m < TOPK) ? m : TOPK;
    unsigned int prev = 0xFFFFFFFFu;
    for (int s = 0; s < kcount; s++) {
        unsigned int best = 0;  // valid keys are > 0 (overlap >= 12)
        for (int i = t; i < m; i += 256) {
            unsigned int k = (unsigned int)w[256 + i];
            if (k < prev && k > best) best = k;
        }
        __syncthreads();          // protect s_red reads from prev iteration
        s_red[t] = best;
        __syncthreads();
        for (int off = 128; off > 0; off >>= 1) {
            if (t < off) s_red[t] = s_red[t] > s_red[t + off] ? s_red[t] : s_red[t + off];
            __syncthreads();
        }
        prev = s_red[0];          // strictly-descending unique keys
        if (t == 0) s_top[s] = prev;
    }
    __syncthreads();
    // contents: [32, 384]; zero below-threshold / empty slots
    for (int i = t; i < TOPK * CDIM; i += 256) {
        int s = i / CDIM, d = i - s * CDIM;
        float val = 0.0f;
        if (s < kcount) {
            int idx = CAPACITY - 1 - (int)(s_top[s] & 0x1FFFFu);
            val = content[(size_t)idx * CDIM + d];
        }
        out[i] = val;
    }
    // top_sim: [32]
    if (t < TOPK) {
        float sv = 0.0f;
        if (t < kcount) sv = (float)(s_top[t] >> 17) / 40.0f;
        out[TOPK * CDIM + t] = sv;
    }
}

extern "C" void kernel_launch(void* const* d_in, const int* in_sizes, int n_in,
                              void* d_out, int out_size, void* d_ws, size_t ws_size,
                              hipStream_t stream) {
    const float* query   = (const float*)d_in[0];
    const float* bank    = (const float*)d_in[1];
    const float* content = (const float*)d_in[2];
    const int* mask      = (const int*)d_in[3];  // bool -> int32 per harness
    float* out = (float*)d_out;
    int* w = (int*)d_ws;

    size_t words = ws_size / 4;
    int cap = (int)((words > 256) ? (words - 256) : 0);
    if (cap > 65536) cap = 65536;

    k_prep<<<1, 256, 0, stream>>>(query, w);
    // 1 wave per row, 4 waves per block
    k_overlap<<<CAPACITY / 4, 256, 0, stream>>>(bank, mask, w, cap);
    k_select<<<1, 256, 0, stream>>>(content, w, out, cap);
}

// Round 3
// 1357.245 us; speedup vs baseline: 1.0021x; 1.0021x over previous
//
#include <hip/hip_runtime.h>
#include <stdint.h>

#define SDR_SIZE   2048
#define CAPACITY   131072
#define TOPK       32
#define CDIM       384
#define RPW        8          // rows per wave

// ws layout (int32 words):
// [0]       n_act
// [4..131]  sorted active column indices (cap 128)
// [192]     candidate count
// [256..]   candidate keys: (overlap << 17) | (131071 - row)

__global__ void k_prep(const float* __restrict__ q, int* __restrict__ w) {
    __shared__ int s_cnt;
    __shared__ int s_act[256];
    if (threadIdx.x == 0) s_cnt = 0;
    __syncthreads();
    for (int j = threadIdx.x; j < SDR_SIZE; j += 256) {
        if (q[j] != 0.0f) {
            int p = atomicAdd(&s_cnt, 1);
            if (p < 256) s_act[p] = j;
        }
    }
    __syncthreads();
    if (threadIdx.x == 0) {
        int n = s_cnt < 128 ? s_cnt : 128;
        // insertion sort (n ~ 40) — sorted cols maximize line sharing
        for (int i = 1; i < n; i++) {
            int v = s_act[i]; int k = i - 1;
            while (k >= 0 && s_act[k] > v) { s_act[k + 1] = s_act[k]; k--; }
            s_act[k + 1] = v;
        }
        w[0] = n;
        w[192] = 0;  // reset candidate counter
        for (int i = 0; i < n; i++) w[4 + i] = s_act[i];
    }
}

// 8 rows per wave, 8 lanes per row, ~5 cols per lane. Full lane utilization,
// 16384 waves (64/CU) for TLP; segmented reduce via 3 shuffles.
__global__ __launch_bounds__(256) void k_overlap(const float* __restrict__ bank,
                                                 const int* __restrict__ mask,  // bool -> int32
                                                 int* __restrict__ w, int cap) {
    const int wave = (blockIdx.x * 256 + (int)threadIdx.x) >> 6;
    const int lane = threadIdx.x & 63;
    const int sub  = lane & 7;        // column-group slot within the row
    const int row  = wave * RPW + (lane >> 3);
    const int nact = w[0];            // L1/L2-resident after first touch
    const float* rp = bank + (size_t)row * SDR_SIZE;
    int ov = 0;
    for (int idx = sub; idx < nact; idx += 8) {
        int c = w[4 + idx];           // hot table
        ov += (rp[c] != 0.0f) ? 1 : 0;  // the only HBM gather
    }
    // reduce across the 8 lanes of this row's group
    ov += __shfl_xor(ov, 1);
    ov += __shfl_xor(ov, 2);
    ov += __shfl_xor(ov, 4);
    if (sub == 0) {
        float sim = (float)ov / 40.0f;
        if (mask[row] != 0 && sim >= 0.3f) {
            int p = atomicAdd(&w[192], 1);
            if (p < cap) w[256 + p] = (ov << 17) | (131071 - row);
        }
    }
}

__global__ void k_select(const float* __restrict__ content,
                         const int* __restrict__ w,
                         float* __restrict__ out, int cap) {
    __shared__ unsigned int s_top[TOPK];
    int t = threadIdx.x;
    int m = w[192];
    if (m > cap) m = cap;
    int kcount = (m < TOPK) ? m : TOPK;
    if (t < 64) {
        // single-wave repeated strict-max over unique keys
        unsigned int prev = 0xFFFFFFFFu;
        for (int s = 0; s < kcount; s++) {
            unsigned int best = 0;  // valid keys > 0 (overlap >= 12)
            for (int i = t; i < m; i += 64) {
                unsigned int k = (unsigned int)w[256 + i];
                if (k < prev && k > best) best = k;
            }
            for (int off = 1; off < 64; off <<= 1) {
                unsigned int o = (unsigned int)__shfl_xor((int)best, off);
                best = o > best ? o : best;
            }
            prev = best;            // all 64 lanes agree
            if (t == 0) s_top[s] = best;
        }
    }
    __syncthreads();
    // contents: [32, 384]; zero below-threshold / empty slots
    for (int i = t; i < TOPK * CDIM; i += 256) {
        int s = i / CDIM, d = i - s * CDIM;
        float val = 0.0f;
        if (s < kcount) {
            int idx = CAPACITY - 1 - (int)(s_top[s] & 0x1FFFFu);
            val = content[(size_t)idx * CDIM + d];
        }
        out[i] = val;
    }
    // top_sim: [32]
    if (t < TOPK) {
        float sv = 0.0f;
        if (t < kcount) sv = (float)(s_top[t] >> 17) / 40.0f;
        out[TOPK * CDIM + t] = sv;
    }
}

extern "C" void kernel_launch(void* const* d_in, const int* in_sizes, int n_in,
                              void* d_out, int out_size, void* d_ws, size_t ws_size,
                              hipStream_t stream) {
    const float* query   = (const float*)d_in[0];
    const float* bank    = (const float*)d_in[1];
    const float* content = (const float*)d_in[2];
    const int* mask      = (const int*)d_in[3];  // bool -> int32 per harness
    float* out = (float*)d_out;
    int* w = (int*)d_ws;

    size_t words = ws_size / 4;
    int cap = (int)((words > 256) ? (words - 256) : 0);
    if (cap > 65536) cap = 65536;

    k_prep<<<1, 256, 0, stream>>>(query, w);
    // 8 rows/wave, 4 waves/block -> 32 rows/block
    k_overlap<<<CAPACITY / (RPW * 4), 256, 0, stream>>>(bank, mask, w, cap);
    k_select<<<1, 256, 0, stream>>>(content, w, out, cap);
}